// Round 4
// baseline (1245.694 us; speedup 1.0000x reference)
//
#include <hip/hip_runtime.h>
#include <hip/hip_bf16.h>
#include <math.h>

typedef __bf16 bf16x8 __attribute__((ext_vector_type(8)));
typedef float f32x4 __attribute__((ext_vector_type(4)));

constexpr int D  = 128;
constexpr int LQ = 2048;
constexpr int SK = 2048;
constexpr int BM = 64;   // queries per block (4 waves x 16 rows)
constexpr int BN = 64;   // keys per K-loop iteration
constexpr int VT_STRIDE = 72;  // Vt LDS row stride (elements)
constexpr int PS_STRIDE = 72;  // Ps LDS row stride

__device__ inline bf16x8 cvt8(f32x4 a, f32x4 b) {
  bf16x8 r;
  r[0] = (__bf16)a[0]; r[1] = (__bf16)a[1]; r[2] = (__bf16)a[2]; r[3] = (__bf16)a[3];
  r[4] = (__bf16)b[0]; r[5] = (__bf16)b[1]; r[6] = (__bf16)b[2]; r[7] = (__bf16)b[3];
  return r;
}

// Flash-style GQA fwd: fp32 in, fp32 out, bf16 MFMA with hi/lo split on QK^T.
// Layouts (HW-verified m89/m91/m120):
//   A: A[m=lane&15][k=quad*8+j]; B: B[k=quad*8+j][n=lane&15]; C/D: row=4*quad+r, col=lane&15.
__global__ __launch_bounds__(256, 2)
void gqa_fwd(const float* __restrict__ qg, const float* __restrict__ kg,
             const float* __restrict__ vg, float* __restrict__ outg)
{
  __shared__ alignas(16) __bf16 Vt[D * VT_STRIDE];   // V tile transposed [d][s]
  __shared__ alignas(16) __bf16 Ps[BM * PS_STRIDE];  // P tile (C-layout -> A-layout)

  const int bid   = blockIdx.x;
  const int bhg   = bid >> 5;        // 0..63 = ((b*8+h)*4+g)
  const int qtile = bid & 31;
  const int bh    = bhg >> 2;        // KV head 0..15

  const int tid  = threadIdx.x;
  const int wave = tid >> 6;
  const int lane = tid & 63;
  const int i16  = lane & 15;
  const int quad = lane >> 4;

  const float* qbase = qg + (size_t)bhg * (LQ * D) + (size_t)(qtile * BM) * D;
  const float* kbase = kg + (size_t)bh * (SK * D);
  const float* vbase = vg + (size_t)bh * (SK * D);

  // ---- Q fragments, persistent, hi/lo bf16 split (wave w owns rows [16w,16w+16))
  bf16x8 qhi[4], qlo[4];
  {
    const float* qp = qbase + (size_t)(16 * wave + i16) * D + 8 * quad;
#pragma unroll
    for (int t = 0; t < 4; ++t) {
      f32x4 a = *(const f32x4*)(qp + 32 * t);
      f32x4 b = *(const f32x4*)(qp + 32 * t + 4);
      qhi[t] = cvt8(a, b);
#pragma unroll
      for (int j = 0; j < 4; ++j) {
        qlo[t][j]     = (__bf16)(a[j] - (float)qhi[t][j]);
        qlo[t][j + 4] = (__bf16)(b[j] - (float)qhi[t][j + 4]);
      }
    }
  }

  f32x4 o_acc[8];
#pragma unroll
  for (int c = 0; c < 8; ++c) o_acc[c] = (f32x4){0.f, 0.f, 0.f, 0.f};
  float m_r[4], l_r[4];
#pragma unroll
  for (int r = 0; r < 4; ++r) { m_r[r] = -INFINITY; l_r[r] = 0.f; }

  const int vs    = tid & 63;          // V staging: s within tile
  const int vdblk = (tid >> 6) * 32;   // V staging: d block

  for (int it = 0; it < SK / BN; ++it) {
    const int s0 = it * BN;
    __syncthreads();  // prior iter's Vt reads complete before restage

    // ---- stage V tile transposed into LDS: Vt[d][s] = (bf16)V[s0+s][d]
#pragma unroll
    for (int r = 0; r < 4; ++r) {
      const int d0 = vdblk + r * 8;
      const float* vp = vbase + (size_t)(s0 + vs) * D + d0;
      bf16x8 vload = cvt8(*(const f32x4*)vp, *(const f32x4*)(vp + 4));
#pragma unroll
      for (int j = 0; j < 8; ++j) Vt[(d0 + j) * VT_STRIDE + vs] = vload[j];
    }
    __syncthreads();

    // ---- S = Q K^T (hi/lo split: error ~ qlo*klo ~ 2^-16, negligible)
    f32x4 sf[4];
#pragma unroll
    for (int n = 0; n < 4; ++n) sf[n] = (f32x4){0.f, 0.f, 0.f, 0.f};
#pragma unroll
    for (int n = 0; n < 4; ++n) {
      const float* kp = kbase + (size_t)(s0 + 16 * n + i16) * D + 8 * quad;
#pragma unroll
      for (int t = 0; t < 4; ++t) {
        f32x4 a = *(const f32x4*)(kp + 32 * t);
        f32x4 b = *(const f32x4*)(kp + 32 * t + 4);
        bf16x8 khi = cvt8(a, b), klo;
#pragma unroll
        for (int j = 0; j < 4; ++j) {
          klo[j]     = (__bf16)(a[j] - (float)khi[j]);
          klo[j + 4] = (__bf16)(b[j] - (float)khi[j + 4]);
        }
        sf[n] = __builtin_amdgcn_mfma_f32_16x16x32_bf16(qhi[t], khi, sf[n], 0, 0, 0);
        sf[n] = __builtin_amdgcn_mfma_f32_16x16x32_bf16(qlo[t], khi, sf[n], 0, 0, 0);
        sf[n] = __builtin_amdgcn_mfma_f32_16x16x32_bf16(qhi[t], klo, sf[n], 0, 0, 0);
      }
    }

    // ---- online softmax (no 1/sqrt(D) scale, per reference)
    float alpha[4], rs[4];
#pragma unroll
    for (int r = 0; r < 4; ++r) {
      float mx = fmaxf(fmaxf(sf[0][r], sf[1][r]), fmaxf(sf[2][r], sf[3][r]));
      mx = fmaxf(mx, __shfl_xor(mx, 1, 64));
      mx = fmaxf(mx, __shfl_xor(mx, 2, 64));
      mx = fmaxf(mx, __shfl_xor(mx, 4, 64));
      mx = fmaxf(mx, __shfl_xor(mx, 8, 64));
      const float mnew = fmaxf(m_r[r], mx);
      alpha[r] = __expf(m_r[r] - mnew);   // first iter: exp(-inf)=0
      m_r[r] = mnew;
      rs[r] = 0.f;
    }
#pragma unroll
    for (int n = 0; n < 4; ++n) {
#pragma unroll
      for (int r = 0; r < 4; ++r) {
        const float p = __expf(sf[n][r] - m_r[r]);
        const __bf16 pb = (__bf16)p;
        rs[r] += (float)pb;   // l consistent with the bf16 P used in P*V
        Ps[(16 * wave + 4 * quad + r) * PS_STRIDE + 16 * n + i16] = pb;
      }
    }
#pragma unroll
    for (int r = 0; r < 4; ++r) {
      float s = rs[r];
      s += __shfl_xor(s, 1, 64);
      s += __shfl_xor(s, 2, 64);
      s += __shfl_xor(s, 4, 64);
      s += __shfl_xor(s, 8, 64);
      l_r[r] = l_r[r] * alpha[r] + s;
#pragma unroll
      for (int c = 0; c < 8; ++c) o_acc[c][r] *= alpha[r];
    }

    asm volatile("s_waitcnt lgkmcnt(0)" ::: "memory");  // wave-local Ps visible

    // ---- O += P V
    bf16x8 pf[2];
#pragma unroll
    for (int f = 0; f < 2; ++f)
      pf[f] = *(const bf16x8*)&Ps[(16 * wave + i16) * PS_STRIDE + 32 * f + 8 * quad];
#pragma unroll
    for (int c = 0; c < 8; ++c) {
#pragma unroll
      for (int f = 0; f < 2; ++f) {
        bf16x8 vf = *(const bf16x8*)&Vt[(16 * c + i16) * VT_STRIDE + 32 * f + 8 * quad];
        o_acc[c] = __builtin_amdgcn_mfma_f32_16x16x32_bf16(pf[f], vf, o_acc[c], 0, 0, 0);
      }
    }
  }

  // ---- epilogue: divide by row sum, store fp32
  float* obase = outg + (size_t)bhg * (LQ * D) + (size_t)(qtile * BM) * D;
#pragma unroll
  for (int r = 0; r < 4; ++r) {
    const float inv = 1.f / l_r[r];
    float* op = obase + (size_t)(16 * wave + 4 * quad + r) * D + i16;
#pragma unroll
    for (int c = 0; c < 8; ++c) op[16 * c] = o_acc[c][r] * inv;
  }
}

extern "C" void kernel_launch(void* const* d_in, const int* in_sizes, int n_in,
                              void* d_out, int out_size, void* d_ws, size_t ws_size,
                              hipStream_t stream) {
  const float* q = (const float*)d_in[0];
  const float* k = (const float*)d_in[1];
  const float* v = (const float*)d_in[2];
  float* out = (float*)d_out;
  (void)d_ws; (void)ws_size; (void)in_sizes; (void)n_in; (void)out_size;
  dim3 grid(64 * (LQ / BM));  // 2048 blocks
  gqa_fwd<<<grid, 256, 0, stream>>>(q, k, v, out);
}